// Round 3
// baseline (521.886 us; speedup 1.0000x reference)
//
#include <hip/hip_runtime.h>

// VQ: N=262144 rows, DIM=64, K=1024 codes.
// Stage 1: 32x32x16 bf16 MFMA, 3-product hi/lo split, e2+512 folded in via
//   augmented dims 64/65, single chained accumulator -> positive scores.
//   Per-score: key = (bits & ~31) | ct ; 3-op top2 merge. B tiles LDS-staged.
// Stage 2: exact fp32 re-solve of rows flagged with margin < FLAG_EPS.

#define VQ_N 262144
#define VQ_DIM 64
#define VQ_K 1024
#define NT 32                  // 32 code-tiles of 32 codes
#define CHUNKS 640             // 16B chunks per tile (320 hi + 320 lo) = 10240 B
#define FLAG_EPS 1.5e-2f

typedef short short8 __attribute__((ext_vector_type(8)));
typedef float f32x16 __attribute__((ext_vector_type(16)));

// ws layout (bytes)
#define WS_BFRAG 0                   // 32 tiles * 10240 B = 327680
#define WS_E2    (328*1024)          // float[1024] raw ||e||^2 (stage2)
#define WS_FLAGS (332*1024)          // u32[8192], word w covers rows 32w..32w+31
#define WS_NEEDED (364*1024)

static __device__ __forceinline__ unsigned short f2bf_rtne(float f) {
    unsigned u = __float_as_uint(f);
    unsigned r = u + 0x7FFFu + ((u >> 16) & 1u);
    return (unsigned short)(r >> 16);
}
static __device__ __forceinline__ float bf2f(unsigned short h) {
    return __uint_as_float(((unsigned)h) << 16);
}

// ---------------- prep: B fragments (hi/lo, dims 0..79), e2 ----------------
// chunk t in [0, 32*640): 16B = 8 bf16 of B_part[k = 16s+(lane>>5)*8+j][col]
__global__ void vq_prep(const float* __restrict__ embed, unsigned char* __restrict__ ws) {
    int t = blockIdx.x * 256 + threadIdx.x;
    unsigned short* bf = (unsigned short*)(ws + WS_BFRAG);
    float* e2g = (float*)(ws + WS_E2);
    if (t < NT * CHUNKS) {
        int ct = t / CHUNKS;
        int r = t % CHUNKS;
        int arr = (r >= 320) ? 1 : 0;       // 0 = hi, 1 = lo
        int rr = arr ? (r - 320) : r;
        int s = rr >> 6;
        int lane = rr & 63;
        int code = ct * 32 + (lane & 31);
        int kbase = 16 * s + ((lane >> 5) << 3);
        const float* ep = embed + (size_t)code * VQ_DIM;
        short8 pack = {0, 0, 0, 0, 0, 0, 0, 0};
        if (kbase < VQ_DIM) {
#pragma unroll
            for (int j = 0; j < 8; ++j) {
                float v = ep[kbase + j];
                unsigned short h = f2bf_rtne(v);
                pack[j] = arr ? (short)f2bf_rtne(v - bf2f(h)) : (short)h;
            }
        } else if (kbase == VQ_DIM) {
            // dims 64,65 carry e2p = ||e||^2 + 512 split 4 ways (vs A = 1.0)
            float a0 = 0, a1 = 0, a2 = 0, a3 = 0;
#pragma unroll
            for (int j = 0; j < VQ_DIM; j += 4) {
                a0 = fmaf(ep[j], ep[j], a0);
                a1 = fmaf(ep[j + 1], ep[j + 1], a1);
                a2 = fmaf(ep[j + 2], ep[j + 2], a2);
                a3 = fmaf(ep[j + 3], ep[j + 3], a3);
            }
            float e2p = 512.0f + (a0 + a1) + (a2 + a3);
            unsigned short E0 = f2bf_rtne(e2p);
            float r1 = e2p - bf2f(E0);
            unsigned short E1 = f2bf_rtne(r1);
            float r2 = r1 - bf2f(E1);
            unsigned short E2 = f2bf_rtne(r2);
            float r3 = r2 - bf2f(E2);
            unsigned short E3 = f2bf_rtne(r3);
            pack[0] = arr ? (short)E1 : (short)E0;   // dim 64
            pack[1] = arr ? (short)E3 : (short)E2;   // dim 65
        }
        ((short8*)bf)[t] = pack;
    } else if (t < NT * CHUNKS + VQ_K) {
        int code = t - NT * CHUNKS;
        const float* ep = embed + (size_t)code * VQ_DIM;
        float a0 = 0, a1 = 0, a2 = 0, a3 = 0;
#pragma unroll
        for (int j = 0; j < VQ_DIM; j += 4) {
            a0 = fmaf(ep[j], ep[j], a0);
            a1 = fmaf(ep[j + 1], ep[j + 1], a1);
            a2 = fmaf(ep[j + 2], ep[j + 2], a2);
            a3 = fmaf(ep[j + 3], ep[j + 3], a3);
        }
        e2g[code] = (a0 + a1) + (a2 + a3);
    }
}

// ---------------- stage 1 ----------------
__global__ __launch_bounds__(256, 3)
void vq_stage1(const float* __restrict__ x, const float* __restrict__ embed,
               const unsigned char* __restrict__ wsro, unsigned char* __restrict__ ws,
               float* __restrict__ out) {
    __shared__ float4 lds_buf[2][CHUNKS];   // 2 x 10240 B
    __shared__ int idx_s[4][32];

    const int tid = threadIdx.x;
    const int lane = tid & 63;
    const int wave = tid >> 6;
    const int gwave = blockIdx.x * 4 + wave;
    const int R0 = gwave * 32;
    const int row = R0 + (lane & 31);
    const int khalf = (lane >> 5) << 3;     // 0 or 8

    const float4* bsrc = (const float4*)(wsro + WS_BFRAG);
    unsigned* flags = (unsigned*)(ws + WS_FLAGS);

    // A fragments: -2x hi/lo; s=4 is the augmentation step (dims 64..79)
    short8 ah[5], al[5];
#pragma unroll
    for (int s = 0; s < 4; ++s) {
        const float4* xp4 = (const float4*)(x + (size_t)row * VQ_DIM + 16 * s + khalf);
        float4 v0 = xp4[0], v1 = xp4[1];
        float vv[8] = {v0.x, v0.y, v0.z, v0.w, v1.x, v1.y, v1.z, v1.w};
#pragma unroll
        for (int j = 0; j < 8; ++j) {
            float v = -2.0f * vv[j];
            unsigned short h = f2bf_rtne(v);
            ah[s][j] = (short)h;
            al[s][j] = (short)f2bf_rtne(v - bf2f(h));
        }
    }
#pragma unroll
    for (int j = 0; j < 8; ++j) { ah[4][j] = 0; al[4][j] = 0; }
    if (khalf == 0) { ah[4][0] = (short)0x3F80; ah[4][1] = (short)0x3F80; }  // 1.0 at dims 64,65

    const f32x16 zero16 = {0, 0, 0, 0, 0, 0, 0, 0, 0, 0, 0, 0, 0, 0, 0, 0};

    unsigned m1k[16], m2k[16];
#pragma unroll
    for (int r = 0; r < 16; ++r) { m1k[r] = 0xFFFFFFFFu; m2k[r] = 0xFFFFFFFFu; }

    // prologue: stage tile 0
    {
        const float4* src = bsrc;
        float4* d = (float4*)lds_buf[0];
        for (int i = tid; i < CHUNKS; i += 256) d[i] = src[i];
    }
    __syncthreads();

#pragma unroll 2
    for (int ct = 0; ct < NT; ++ct) {
        // T14: issue next tile's global loads before compute
        float4 st0, st1, st2;
        const bool has = (ct + 1) < NT;
        if (has) {
            const float4* src = bsrc + (size_t)(ct + 1) * CHUNKS;
            st0 = src[tid];
            st1 = src[tid + 256];
            if (tid < 128) st2 = src[tid + 512];
        }

        const short8* bhp = (const short8*)lds_buf[ct & 1];
        const short8* blp = bhp + 320;

        f32x16 acc;
        // lh: al . bh  (s=4 term is zero: al[4]==0)
        acc = __builtin_amdgcn_mfma_f32_32x32x16_bf16(al[0], bhp[0 * 64 + lane], zero16, 0, 0, 0);
        acc = __builtin_amdgcn_mfma_f32_32x32x16_bf16(al[1], bhp[1 * 64 + lane], acc, 0, 0, 0);
        acc = __builtin_amdgcn_mfma_f32_32x32x16_bf16(al[2], bhp[2 * 64 + lane], acc, 0, 0, 0);
        acc = __builtin_amdgcn_mfma_f32_32x32x16_bf16(al[3], bhp[3 * 64 + lane], acc, 0, 0, 0);
        // hl: ah . bl
        acc = __builtin_amdgcn_mfma_f32_32x32x16_bf16(ah[0], blp[0 * 64 + lane], acc, 0, 0, 0);
        acc = __builtin_amdgcn_mfma_f32_32x32x16_bf16(ah[1], blp[1 * 64 + lane], acc, 0, 0, 0);
        acc = __builtin_amdgcn_mfma_f32_32x32x16_bf16(ah[2], blp[2 * 64 + lane], acc, 0, 0, 0);
        acc = __builtin_amdgcn_mfma_f32_32x32x16_bf16(ah[3], blp[3 * 64 + lane], acc, 0, 0, 0);
        acc = __builtin_amdgcn_mfma_f32_32x32x16_bf16(ah[4], blp[4 * 64 + lane], acc, 0, 0, 0);
        // hh: ah . bh (carries e2p at dims 64,65)
        acc = __builtin_amdgcn_mfma_f32_32x32x16_bf16(ah[0], bhp[0 * 64 + lane], acc, 0, 0, 0);
        acc = __builtin_amdgcn_mfma_f32_32x32x16_bf16(ah[1], bhp[1 * 64 + lane], acc, 0, 0, 0);
        acc = __builtin_amdgcn_mfma_f32_32x32x16_bf16(ah[2], bhp[2 * 64 + lane], acc, 0, 0, 0);
        acc = __builtin_amdgcn_mfma_f32_32x32x16_bf16(ah[3], bhp[3 * 64 + lane], acc, 0, 0, 0);
        acc = __builtin_amdgcn_mfma_f32_32x32x16_bf16(ah[4], bhp[4 * 64 + lane], acc, 0, 0, 0);

        // scores are positive floats -> bits order-preserving; pack ct in low 5
        unsigned ctu = (unsigned)ct;
#pragma unroll
        for (int r = 0; r < 16; ++r) {
            unsigned key = (__float_as_uint(acc[r]) & 0xFFFFFFE0u) | ctu;
            unsigned t1 = m1k[r] > key ? m1k[r] : key;
            m2k[r] = m2k[r] < t1 ? m2k[r] : t1;
            m1k[r] = m1k[r] < key ? m1k[r] : key;
        }

        // write staged tile to the other buffer
        if (has) {
            float4* d = (float4*)lds_buf[(ct + 1) & 1];
            d[tid] = st0;
            d[tid + 256] = st1;
            if (tid < 128) d[tid + 512] = st2;
        }
        __syncthreads();
    }

    // cross-lane reduce over the 32 cols (lanes sharing (lane>>5) half)
    unsigned res[16];
#pragma unroll
    for (int r = 0; r < 16; ++r) res[r] = (unsigned)(lane & 31);
#pragma unroll
    for (int m = 1; m <= 16; m <<= 1) {
#pragma unroll
        for (int r = 0; r < 16; ++r) {
            unsigned ok = (unsigned)__shfl_xor((int)m1k[r], m);
            unsigned ok2 = (unsigned)__shfl_xor((int)m2k[r], m);
            unsigned orr = (unsigned)__shfl_xor((int)res[r], m);
            unsigned t1 = m1k[r] > ok ? m1k[r] : ok;
            unsigned c2 = ok2 < t1 ? ok2 : t1;
            m2k[r] = m2k[r] < c2 ? m2k[r] : c2;
            bool take = (ok < m1k[r]) || (ok == m1k[r] && orr < res[r]);
            if (take) { m1k[r] = ok; res[r] = orr; }
        }
    }

    // lanes 0 and 32 publish idx + flags for their 16 rows
    const int h = lane >> 5;
    unsigned fmask = 0;
    if ((lane & 31) == 0) {
#pragma unroll
        for (int r = 0; r < 16; ++r) {
            int rl = (r & 3) + 8 * (r >> 2) + 4 * h;
            int code = (int)((m1k[r] & 31u) * 32u + res[r]);
            idx_s[wave][rl] = code;
            float s1 = __uint_as_float(m1k[r] & 0xFFFFFFE0u);
            float s2 = __uint_as_float(m2k[r] & 0xFFFFFFE0u);
            if (s2 - s1 < FLAG_EPS) fmask |= 1u << rl;
        }
    }
    unsigned fother = (unsigned)__shfl_xor((int)fmask, 32);
    if (lane == 0) flags[gwave] = fmask | fother;   // whole word owned by this wave

    // gather embed[idx] -> out (2 lanes per row, fully coalesced)
    const int orow = lane >> 1;
    const int ohalf = lane & 1;
    int code = idx_s[wave][orow];
    const float4* ep = (const float4*)(embed + (size_t)code * VQ_DIM) + ohalf * 8;
    float4* op = (float4*)(out + (size_t)(R0 + orow) * VQ_DIM) + ohalf * 8;
#pragma unroll
    for (int j = 0; j < 8; ++j) op[j] = ep[j];
}

// ---------------- stage 2: exact fp32 re-solve of flagged rows ----------------
__global__ __launch_bounds__(256, 4)
void vq_stage2(const float* __restrict__ x, const float* __restrict__ embed,
               const unsigned char* __restrict__ ws, float* __restrict__ out) {
    const unsigned* flags = (const unsigned*)(ws + WS_FLAGS);
    const float* e2 = (const float*)(ws + WS_E2);
    int lane = threadIdx.x & 63;
    int wave = threadIdx.x >> 6;
    int w = blockIdx.x * 4 + wave;
    int rowbase = w * 64;
    unsigned fw = flags[(rowbase >> 5) + (lane >> 5)];
    int bit = (fw >> (lane & 31)) & 1;
    unsigned long long ball = __ballot(bit);
    while (ball) {
        int b = __ffsll(ball) - 1;
        ball &= ball - 1;
        int row = rowbase + b;
        const float* xr = x + (size_t)row * VQ_DIM;
        float best = __builtin_inff();
        int bi = VQ_K;
        for (int t = 0; t < VQ_K / 64; ++t) {
            int c = t * 64 + lane;
            const float* ep = embed + (size_t)c * VQ_DIM;
            float a0 = 0, a1 = 0, a2 = 0, a3 = 0;
#pragma unroll
            for (int j = 0; j < VQ_DIM; j += 4) {
                a0 = fmaf(xr[j], ep[j], a0);
                a1 = fmaf(xr[j + 1], ep[j + 1], a1);
                a2 = fmaf(xr[j + 2], ep[j + 2], a2);
                a3 = fmaf(xr[j + 3], ep[j + 3], a3);
            }
            float dot = (a0 + a1) + (a2 + a3);
            float s = fmaf(-2.0f, dot, e2[c]);
            if (s < best) { best = s; bi = c; }
        }
#pragma unroll
        for (int m = 1; m <= 32; m <<= 1) {
            float ob = __shfl_xor(best, m);
            int oi = __shfl_xor(bi, m);
            if (ob < best || (ob == best && oi < bi)) { best = ob; bi = oi; }
        }
        out[(size_t)row * VQ_DIM + lane] = embed[(size_t)bi * VQ_DIM + lane];
    }
}

// ---------------- fallback (round-1 fp32) ----------------
__global__ __launch_bounds__(256, 4)
void vq_fallback(const float* __restrict__ x, const float* __restrict__ embed,
                 float* __restrict__ out) {
    __shared__ float e2s[VQ_K];
    const int tid = threadIdx.x;
    for (int c = tid; c < VQ_K; c += 256) {
        const float4* ep = (const float4*)(embed + c * VQ_DIM);
        float s = 0.0f;
#pragma unroll
        for (int j = 0; j < VQ_DIM / 4; ++j) {
            float4 v = ep[j];
            s = fmaf(v.x, v.x, s); s = fmaf(v.y, v.y, s);
            s = fmaf(v.z, v.z, s); s = fmaf(v.w, v.w, s);
        }
        e2s[c] = s;
    }
    __syncthreads();
    const int row = blockIdx.x * 256 + tid;
    float xr[VQ_DIM];
    const float4* xp = (const float4*)(x + (size_t)row * VQ_DIM);
#pragma unroll
    for (int j = 0; j < VQ_DIM / 4; ++j) {
        float4 v = xp[j];
        xr[4 * j] = v.x; xr[4 * j + 1] = v.y; xr[4 * j + 2] = v.z; xr[4 * j + 3] = v.w;
    }
    float best = __builtin_inff();
    int bidx = 0;
    for (int c = 0; c < VQ_K; ++c) {
        const float4* ep = (const float4*)(embed + c * VQ_DIM);
        float a0 = 0, a1 = 0, a2 = 0, a3 = 0;
#pragma unroll
        for (int j = 0; j < VQ_DIM / 4; ++j) {
            float4 v = ep[j];
            a0 = fmaf(xr[4 * j], v.x, a0);
            a1 = fmaf(xr[4 * j + 1], v.y, a1);
            a2 = fmaf(xr[4 * j + 2], v.z, a2);
            a3 = fmaf(xr[4 * j + 3], v.w, a3);
        }
        float score = fmaf(-2.0f, (a0 + a1) + (a2 + a3), e2s[c]);
        if (score < best) { best = score; bidx = c; }
    }
    const float4* bp = (const float4*)(embed + (size_t)bidx * VQ_DIM);
    float4* op = (float4*)(out + (size_t)row * VQ_DIM);
#pragma unroll
    for (int j = 0; j < VQ_DIM / 4; ++j) op[j] = bp[j];
}

extern "C" void kernel_launch(void* const* d_in, const int* in_sizes, int n_in,
                              void* d_out, int out_size, void* d_ws, size_t ws_size,
                              hipStream_t stream) {
    const float* x = (const float*)d_in[0];
    const float* embed = (const float*)d_in[1];
    float* out = (float*)d_out;
    if (ws_size < WS_NEEDED) {
        hipLaunchKernelGGL(vq_fallback, dim3(VQ_N / 256), dim3(256), 0, stream, x, embed, out);
        return;
    }
    unsigned char* ws = (unsigned char*)d_ws;
    hipLaunchKernelGGL(vq_prep, dim3(84), dim3(256), 0, stream, embed, ws);
    hipLaunchKernelGGL(vq_stage1, dim3(VQ_N / 128), dim3(256), 0, stream, x, embed, ws, ws, out);
    hipLaunchKernelGGL(vq_stage2, dim3(VQ_N / 256), dim3(256), 0, stream, x, embed, ws, out);
}